// Round 1
// baseline (21260.498 us; speedup 1.0000x reference)
//
#include <hip/hip_runtime.h>

// ---------------------------------------------------------------------------
// DenseFeatureExtractionModule (AP, OS4): 10x conv3x3 VGG-ish trunk with
// 2 maxpools, irregular 2x2 pooling (mask-gated), and 3 graph convs with
// spatially-varying dilation (1 or 2, per-pixel from pooling_mask).
// Round 1: correct fp32 direct conv. All conv layers VALU-bound by design:
// 288 FMA per ci-channel per thread vs ~24 LDS reads; weights go through the
// scalar pipe (block-uniform addresses).
// ---------------------------------------------------------------------------

#define TS 32         // spatial tile (32x32 outputs per block)
#define IST1 36       // LDS row stride for halo-1 tile (34 cols padded to 36, %4==0)
#define IST2 37       // LDS row stride for halo-2 tile (36 cols padded to 37)

// ---------------- dense 3x3 conv (dil=1, SAME, relu) ----------------
// block (8,16) = 128 threads; each thread computes 2(y) x 4(x) pixels x 4 couts.
__global__ __launch_bounds__(128)
void conv3x3_relu(const float* __restrict__ in, const float* __restrict__ wgt,
                  const float* __restrict__ bias, float* __restrict__ out,
                  int B, int Cin, int Cout, int H, int W)
{
    const int tilesX = W / TS;
    const int tx0 = (blockIdx.x % tilesX) * TS;
    const int ty0 = (blockIdx.x / tilesX) * TS;
    const int co0 = blockIdx.y * 4;
    const int b   = blockIdx.z;

    __shared__ __align__(16) float s_in[4][TS + 2][IST1];

    const int tid = threadIdx.y * 8 + threadIdx.x;
    const int xl  = threadIdx.x * 4;   // 0..28
    const int yl  = threadIdx.y * 2;   // 0..30

    float acc[4][2][4];
    #pragma unroll
    for (int co = 0; co < 4; ++co)
        #pragma unroll
        for (int py = 0; py < 2; ++py)
            #pragma unroll
            for (int px = 0; px < 4; ++px) acc[co][py][px] = 0.f;

    for (int ci0 = 0; ci0 < Cin; ci0 += 4) {
        // cooperative load: 4 channels x 34 x 34 (halo 1), zero-fill OOB
        for (int i = tid; i < 4 * 34 * 34; i += 128) {
            int ci = i / (34 * 34);
            int r  = i % (34 * 34);
            int iy = r / 34, ix = r % 34;
            int gy = ty0 - 1 + iy, gx = tx0 - 1 + ix;
            int c  = ci0 + ci;
            float v = 0.f;
            if (c < Cin && gy >= 0 && gy < H && gx >= 0 && gx < W)
                v = in[((b * Cin + c) * H + gy) * W + gx];
            s_in[ci][iy][ix] = v;
        }
        __syncthreads();

        #pragma unroll
        for (int ci = 0; ci < 4; ++ci) {
            if ((ci0 + ci) < Cin) {   // uniform branch (only layer 1 has Cin=3)
                float iv[4][6];
                #pragma unroll
                for (int r = 0; r < 4; ++r)
                    #pragma unroll
                    for (int c = 0; c < 6; ++c)
                        iv[r][c] = s_in[ci][yl + r][xl + c];
                #pragma unroll
                for (int co = 0; co < 4; ++co) {
                    const float* wp = wgt + ((size_t)(co0 + co) * Cin + (ci0 + ci)) * 9;
                    #pragma unroll
                    for (int ky = 0; ky < 3; ++ky)
                        #pragma unroll
                        for (int kx = 0; kx < 3; ++kx) {
                            float wv = wp[ky * 3 + kx];  // block-uniform -> s_load
                            #pragma unroll
                            for (int py = 0; py < 2; ++py)
                                #pragma unroll
                                for (int px = 0; px < 4; ++px)
                                    acc[co][py][px] =
                                        fmaf(wv, iv[py + ky][px + kx], acc[co][py][px]);
                        }
                }
            }
        }
        __syncthreads();
    }

    #pragma unroll
    for (int co = 0; co < 4; ++co) {
        float bv = bias[co0 + co];
        #pragma unroll
        for (int py = 0; py < 2; ++py) {
            float4 v;
            v.x = fmaxf(acc[co][py][0] + bv, 0.f);
            v.y = fmaxf(acc[co][py][1] + bv, 0.f);
            v.z = fmaxf(acc[co][py][2] + bv, 0.f);
            v.w = fmaxf(acc[co][py][3] + bv, 0.f);
            float* op = out + ((size_t)(b * Cout + co0 + co) * H + (ty0 + yl + py)) * W
                        + tx0 + xl;
            *(float4*)op = v;
        }
    }
}

// ---------------- graph conv: 3x3, per-pixel dilation 1 or 2, relu ----------
// block (16,16) = 256 threads; each thread owns an ALIGNED 2x2 pixel block
// (mask constant over 2x2 blocks -> d uniform per thread) x 8 couts.
__global__ __launch_bounds__(256)
void gconv3x3_relu(const float* __restrict__ in, const int* __restrict__ mask,
                   const float* __restrict__ wgt, const float* __restrict__ bias,
                   float* __restrict__ out,
                   int B, int Cin, int Cout, int H, int W)
{
    const int tilesX = W / TS;
    const int tx0 = (blockIdx.x % tilesX) * TS;
    const int ty0 = (blockIdx.x / tilesX) * TS;
    const int co0 = blockIdx.y * 8;
    const int b   = blockIdx.z;

    __shared__ __align__(16) float s_in[4][TS + 4][IST2];  // halo 2: 36 rows

    const int tid = threadIdx.y * 16 + threadIdx.x;
    const int lx  = threadIdx.x * 2;
    const int ly  = threadIdx.y * 2;
    const int gy0 = ty0 + ly, gx0 = tx0 + lx;

    const int m = mask[((size_t)b * (H >> 1) + (gy0 >> 1)) * (W >> 1) + (gx0 >> 1)];
    const int d = m ? 2 : 1;            // per-thread (uniform over its 2x2 block)
    const int dr = d * IST2;

    float acc[8][2][2];
    #pragma unroll
    for (int co = 0; co < 8; ++co)
        #pragma unroll
        for (int py = 0; py < 2; ++py)
            #pragma unroll
            for (int px = 0; px < 2; ++px) acc[co][py][px] = 0.f;

    for (int ci0 = 0; ci0 < Cin; ci0 += 4) {      // Cin is 256/512: no tail
        for (int i = tid; i < 4 * 36 * 36; i += 256) {
            int ci = i / (36 * 36);
            int r  = i % (36 * 36);
            int iy = r / 36, ix = r % 36;
            int gy = ty0 - 2 + iy, gx = tx0 - 2 + ix;
            float v = 0.f;
            if (gy >= 0 && gy < H && gx >= 0 && gx < W)
                v = in[((size_t)(b * Cin + ci0 + ci) * H + gy) * W + gx];
            s_in[ci][iy][ix] = v;
        }
        __syncthreads();

        #pragma unroll
        for (int ci = 0; ci < 4; ++ci) {
            float t[2][2][9];
            #pragma unroll
            for (int py = 0; py < 2; ++py)
                #pragma unroll
                for (int px = 0; px < 2; ++px) {
                    const float* cp = &s_in[ci][2 + ly + py][2 + lx + px];
                    #pragma unroll
                    for (int ky = 0; ky < 3; ++ky)
                        #pragma unroll
                        for (int kx = 0; kx < 3; ++kx)
                            t[py][px][ky * 3 + kx] = cp[(ky - 1) * dr + (kx - 1) * d];
                }
            #pragma unroll
            for (int co = 0; co < 8; ++co) {
                const float* wp = wgt + ((size_t)(co0 + co) * Cin + (ci0 + ci)) * 9;
                #pragma unroll
                for (int k = 0; k < 9; ++k) {
                    float wv = wp[k];   // block-uniform -> scalar pipe
                    #pragma unroll
                    for (int py = 0; py < 2; ++py)
                        #pragma unroll
                        for (int px = 0; px < 2; ++px)
                            acc[co][py][px] = fmaf(wv, t[py][px][k], acc[co][py][px]);
                }
            }
        }
        __syncthreads();
    }

    #pragma unroll
    for (int co = 0; co < 8; ++co) {
        float bv = bias[co0 + co];
        #pragma unroll
        for (int py = 0; py < 2; ++py) {
            float2 v;
            v.x = fmaxf(acc[co][py][0] + bv, 0.f);
            v.y = fmaxf(acc[co][py][1] + bv, 0.f);
            *(float2*)(out + ((size_t)(b * Cout + co0 + co) * H + gy0 + py) * W + gx0) = v;
        }
    }
}

// ---------------- 2x2 max pool (stride 2) ----------------
__global__ __launch_bounds__(256)
void maxpool2_kernel(const float* __restrict__ in, float* __restrict__ out,
                     int BC, int H, int W)
{
    int Ho = H >> 1, Wo = W >> 1;
    int n = BC * Ho * Wo;
    int i = blockIdx.x * 256 + threadIdx.x;
    if (i >= n) return;
    int x = i % Wo; int r = i / Wo; int y = r % Ho; int bc = r / Ho;
    const float* p = in + ((size_t)bc * H + 2 * y) * W + 2 * x;
    out[i] = fmaxf(fmaxf(p[0], p[1]), fmaxf(p[W], p[W + 1]));
}

// ---------------- irregular pool: masked 2x2 maxpool, value replicated ------
__global__ __launch_bounds__(256)
void irpool_kernel(const float* __restrict__ in, const int* __restrict__ mask,
                   float* __restrict__ out, int B, int C, int H, int W)
{
    int n = B * C * H * W;
    int i = blockIdx.x * 256 + threadIdx.x;
    if (i >= n) return;
    int x = i % W; int r = i / W; int y = r % H; r /= H; int c = r % C; int b = r / C;
    int m = mask[((size_t)b * (H >> 1) + (y >> 1)) * (W >> 1) + (x >> 1)];
    float v;
    if (m) {
        int y0 = y & ~1, x0 = x & ~1;
        const float* p = in + ((size_t)(b * C + c) * H + y0) * W + x0;
        v = fmaxf(fmaxf(p[0], p[1]), fmaxf(p[W], p[W + 1]));
    } else {
        v = in[i];
    }
    out[i] = v;
}

// ---------------------------------------------------------------------------
extern "C" void kernel_launch(void* const* d_in, const int* in_sizes, int n_in,
                              void* d_out, int out_size, void* d_ws, size_t ws_size,
                              hipStream_t stream)
{
    const float* x    = (const float*)d_in[0];
    const int*   mask = (const int*)d_in[1];
    const float* Wt[10]; const float* bs[10];
    for (int i = 0; i < 10; ++i) {
        Wt[i] = (const float*)d_in[2 + 2 * i];
        bs[i] = (const float*)d_in[3 + 2 * i];
    }

    // ping-pong buffers, each sized for the largest tensor (4 x 64 x 384 x 384)
    const size_t SZ = (size_t)4 * 64 * 384 * 384;
    float* A  = (float*)d_ws;
    float* Bb = A + SZ;

    dim3 cblk(8, 16);
    dim3 gblk(16, 16);

    // L1: 3 -> 64 @ 384
    conv3x3_relu<<<dim3(12 * 12, 64 / 4, 4), cblk, 0, stream>>>(x, Wt[0], bs[0], A, 4, 3, 64, 384, 384);
    // L2: 64 -> 64 @ 384
    conv3x3_relu<<<dim3(12 * 12, 64 / 4, 4), cblk, 0, stream>>>(A, Wt[1], bs[1], Bb, 4, 64, 64, 384, 384);
    // maxpool -> 192
    maxpool2_kernel<<<(4 * 64 * 192 * 192 + 255) / 256, 256, 0, stream>>>(Bb, A, 4 * 64, 384, 384);
    // L3: 64 -> 128 @ 192
    conv3x3_relu<<<dim3(6 * 6, 128 / 4, 4), cblk, 0, stream>>>(A, Wt[2], bs[2], Bb, 4, 64, 128, 192, 192);
    // L4: 128 -> 128 @ 192
    conv3x3_relu<<<dim3(6 * 6, 128 / 4, 4), cblk, 0, stream>>>(Bb, Wt[3], bs[3], A, 4, 128, 128, 192, 192);
    // maxpool -> 96 (OS4)
    maxpool2_kernel<<<(4 * 128 * 96 * 96 + 255) / 256, 256, 0, stream>>>(A, Bb, 4 * 128, 192, 192);
    // L5: 128 -> 256 @ 96
    conv3x3_relu<<<dim3(3 * 3, 256 / 4, 4), cblk, 0, stream>>>(Bb, Wt[4], bs[4], A, 4, 128, 256, 96, 96);
    // L6: 256 -> 256
    conv3x3_relu<<<dim3(3 * 3, 256 / 4, 4), cblk, 0, stream>>>(A, Wt[5], bs[5], Bb, 4, 256, 256, 96, 96);
    // L7: 256 -> 256
    conv3x3_relu<<<dim3(3 * 3, 256 / 4, 4), cblk, 0, stream>>>(Bb, Wt[6], bs[6], A, 4, 256, 256, 96, 96);
    // irregular max-pool (mask-gated)
    irpool_kernel<<<(4 * 256 * 96 * 96 + 255) / 256, 256, 0, stream>>>(A, mask, Bb, 4, 256, 96, 96);
    // L8: gconv 256 -> 512
    gconv3x3_relu<<<dim3(3 * 3, 512 / 8, 4), gblk, 0, stream>>>(Bb, mask, Wt[7], bs[7], A, 4, 256, 512, 96, 96);
    // L9: gconv 512 -> 512
    gconv3x3_relu<<<dim3(3 * 3, 512 / 8, 4), gblk, 0, stream>>>(A, mask, Wt[8], bs[8], Bb, 4, 512, 512, 96, 96);
    // L10: gconv 512 -> 512 -> d_out
    gconv3x3_relu<<<dim3(3 * 3, 512 / 8, 4), gblk, 0, stream>>>(Bb, mask, Wt[9], bs[9], (float*)d_out, 4, 512, 512, 96, 96);

    (void)in_sizes; (void)n_in; (void)out_size; (void)ws_size;
}

// Round 4
// 1568.603 us; speedup vs baseline: 13.5538x; 13.5538x over previous
//
#include <hip/hip_runtime.h>

// ---------------------------------------------------------------------------
// Round 4: full bf16 MFMA pipeline with the staging-coverage FIX.
// Root cause of R2/R3 failures: each LDS row needs 32 ushorts of K-data but
// staging wrote only 8 ushorts per (row,half) slot at element offset half*16,
// leaving elements [8..16) and [24..32) stale -> inf/NaN into MFMA ->
// relu(NaN)=0 (R3 zeros) / inf survival (R2). Fix: 16 ushorts per slot
// (two short8 stores at half*16 and half*16+8), matching global loads.
// ---------------------------------------------------------------------------

typedef __attribute__((ext_vector_type(8))) short short8;
typedef __attribute__((ext_vector_type(4))) float f32x4;

__device__ __forceinline__ float b2f(ushort u) {
    return __uint_as_float(((unsigned)u) << 16);
}
__device__ __forceinline__ ushort f2b(float f) {   // round-to-nearest-even
    unsigned x = __float_as_uint(f);
    x += 0x7FFFu + ((x >> 16) & 1u);
    return (ushort)(x >> 16);
}
__device__ __forceinline__ ushort bmax(ushort a, ushort b) {
    return b2f(a) > b2f(b) ? a : b;
}

// ------------- repack weights [co][ci][t] f32 -> [t][cb][co][ci32] bf16 -----
__global__ __launch_bounds__(256)
void repack_w(const float* __restrict__ w, ushort* __restrict__ wp, int Cin, int Cout)
{
    int n = Cout * Cin * 9;
    int i = blockIdx.x * 256 + threadIdx.x;
    if (i >= n) return;
    int CBl = Cin / 32;
    int c   = i & 31;
    int co  = (i >> 5) % Cout;
    int cbt = i / (32 * Cout);
    int cb  = cbt % CBl;
    int t   = cbt / CBl;
    int ci  = cb * 32 + c;
    wp[i] = f2b(w[((size_t)co * Cin + ci) * 9 + t]);
}

// ------------- L1: 3->64 direct conv, fp32 NCHW in -> bf16 NHWC out ---------
__global__ __launch_bounds__(256)
void l1_conv(const float* __restrict__ in, const float* __restrict__ w,
             const float* __restrict__ bias, ushort* __restrict__ out)
{
    const int H = 384, W = 384;
    __shared__ float s[3][18][18];
    const int tid = threadIdx.x;
    const int tilesX = W / 16;
    const int x0 = (blockIdx.x % tilesX) * 16;
    const int y0 = (blockIdx.x / tilesX) * 16;
    const int b  = blockIdx.z;

    for (int i = tid; i < 3 * 18 * 18; i += 256) {
        int ci = i / (18 * 18);
        int r  = i % (18 * 18);
        int iy = r / 18, ix = r % 18;
        int gy = y0 - 1 + iy, gx = x0 - 1 + ix;
        float v = 0.f;
        if ((unsigned)gy < (unsigned)H && (unsigned)gx < (unsigned)W)
            v = in[((size_t)(b * 3 + ci) * H + gy) * W + gx];
        s[ci][iy][ix] = v;
    }
    __syncthreads();

    const int tx = tid & 15, ty = tid >> 4;
    float iv[3][3][3];
    #pragma unroll
    for (int ci = 0; ci < 3; ++ci)
        #pragma unroll
        for (int ky = 0; ky < 3; ++ky)
            #pragma unroll
            for (int kx = 0; kx < 3; ++kx)
                iv[ci][ky][kx] = s[ci][ty + ky][tx + kx];

    size_t pix = ((size_t)(b * H + y0 + ty) * W + x0 + tx);
    #pragma unroll
    for (int c4 = 0; c4 < 4; ++c4) {
        __align__(16) ushort ob[16];
        #pragma unroll
        for (int co = 0; co < 16; ++co) {
            int coG = c4 * 16 + co;
            float a = bias[coG];
            #pragma unroll
            for (int ci = 0; ci < 3; ++ci)
                #pragma unroll
                for (int ky = 0; ky < 3; ++ky)
                    #pragma unroll
                    for (int kx = 0; kx < 3; ++kx)
                        a = fmaf(w[((size_t)coG * 3 + ci) * 9 + ky * 3 + kx],
                                 iv[ci][ky][kx], a);
            a = a > 0.f ? a : 0.f;
            ob[co] = f2b(a);
        }
        *(short8*)&out[pix * 64 + c4 * 16]     = *(short8*)&ob[0];
        *(short8*)&out[pix * 64 + c4 * 16 + 8] = *(short8*)&ob[8];
    }
}

// ------------- 2x2 maxpool, bf16 NHWC ---------------------------------------
__global__ __launch_bounds__(256)
void maxpool_nhwc(const ushort* __restrict__ in, ushort* __restrict__ out,
                  int Ho, int Wo, int C)
{
    int n = 4 * Ho * Wo * (C / 8);
    int i = blockIdx.x * 256 + threadIdx.x;
    if (i >= n) return;
    int c8 = i % (C / 8);
    int pi = i / (C / 8);
    int x = pi % Wo, y = (pi / Wo) % Ho, b = pi / (Wo * Ho);
    int Hi = Ho * 2, Wi = Wo * 2;
    const ushort* p = in + ((size_t)(b * Hi + 2 * y) * Wi + 2 * x) * C + c8 * 8;
    short8 v00 = *(const short8*)p;
    short8 v01 = *(const short8*)(p + C);
    short8 v10 = *(const short8*)(p + (size_t)Wi * C);
    short8 v11 = *(const short8*)(p + (size_t)Wi * C + C);
    short8 o;
    #pragma unroll
    for (int j = 0; j < 8; ++j)
        o[j] = (short)bmax(bmax((ushort)v00[j], (ushort)v01[j]),
                           bmax((ushort)v10[j], (ushort)v11[j]));
    *(short8*)(out + (size_t)i * 8) = o;
}

// ------------- irregular pool (mask-gated 2x2 max, replicated), NHWC --------
__global__ __launch_bounds__(256)
void irpool_nhwc(const ushort* __restrict__ in, const int* __restrict__ mask,
                 ushort* __restrict__ out)
{
    const int C = 256, H = 96, Wd = 96;
    int n = 4 * H * Wd * (C / 8);
    int i = blockIdx.x * 256 + threadIdx.x;
    if (i >= n) return;
    int c8 = i % (C / 8);
    int pi = i / (C / 8);
    int x = pi % Wd, y = (pi / Wd) % H, b = pi / (Wd * H);
    int m = mask[(b * 48 + (y >> 1)) * 48 + (x >> 1)];
    short8 o;
    if (m) {
        int y0 = y & ~1, x0 = x & ~1;
        const ushort* p = in + ((size_t)(b * H + y0) * Wd + x0) * C + c8 * 8;
        short8 v00 = *(const short8*)p;
        short8 v01 = *(const short8*)(p + C);
        short8 v10 = *(const short8*)(p + (size_t)Wd * C);
        short8 v11 = *(const short8*)(p + (size_t)Wd * C + C);
        #pragma unroll
        for (int j = 0; j < 8; ++j)
            o[j] = (short)bmax(bmax((ushort)v00[j], (ushort)v01[j]),
                               bmax((ushort)v10[j], (ushort)v11[j]));
    } else {
        o = *(const short8*)(in + (size_t)pi * C + c8 * 8);
    }
    *(short8*)(out + (size_t)pi * C + c8 * 8) = o;
}

// ------------- implicit-GEMM conv3x3 (dense/graph), bf16 MFMA ---------------
// 256 threads = 4 waves, wave tile 64x64 (4x4 of mfma_f32_16x16x32_bf16).
// LDS rows: 32 ushorts K-data, stride 40 (80B -> max 2-way bank alias, free).
// STAGING (fixed): each (row,half) slot covers 16 ushorts via two short8s.
template<int BM, int BN, int CIN, int COUT, int H, int W, bool GCONV, bool FINAL>
__global__ __launch_bounds__(256)
void conv_mfma(const ushort* __restrict__ in, const ushort* __restrict__ wp,
               const float* __restrict__ bias, void* __restrict__ outv,
               const int* __restrict__ mask)
{
    constexpr int CB = CIN / 32;
    constexpr int SLOTS = BM * 2 / 256;
    constexpr int WM = BM / 64;
    __shared__ __align__(16) ushort smem[BM * 40 + BN * 40];
    ushort* sA = smem;
    ushort* sB = smem + BM * 40;

    const int tid  = threadIdx.x;
    const int lane = tid & 63;
    const int wv   = tid >> 6;
    const int wm   = wv % WM;
    const int wn   = wv / WM;
    const int col  = lane & 15;
    const int quad = lane >> 4;

    const int bm0 = blockIdx.x * BM;
    const int co0 = blockIdx.y * BN;

    // per-slot pixel coords + dilation (slot = (row pl, half))
    int sy[SLOTS], sx[SLOTS], sb[SLOTS], sd[SLOTS];
    #pragma unroll
    for (int s = 0; s < SLOTS; ++s) {
        int idx = tid + s * 256;
        int p = bm0 + (idx >> 1);
        int b = p / (H * W);
        int r = p - b * (H * W);
        sy[s] = r / W;
        sx[s] = r - sy[s] * W;
        sb[s] = b;
        sd[s] = 1;
        if (GCONV)
            sd[s] = mask[(b * (H / 2) + (sy[s] >> 1)) * (W / 2) + (sx[s] >> 1)] ? 2 : 1;
    }

    f32x4 acc[4][4];
    #pragma unroll
    for (int i = 0; i < 4; ++i)
        #pragma unroll
        for (int j = 0; j < 4; ++j)
            acc[i][j] = (f32x4){0.f, 0.f, 0.f, 0.f};

    for (int t = 0; t < 9; ++t) {
        const int ky = t / 3 - 1, kx = t % 3 - 1;
        // per-slot tap address
        bool   inb[SLOTS];
        size_t abase[SLOTS];
        #pragma unroll
        for (int s = 0; s < SLOTS; ++s) {
            int ys = sy[s] + sd[s] * ky;
            int xs = sx[s] + sd[s] * kx;
            inb[s] = ((unsigned)ys < (unsigned)H) && ((unsigned)xs < (unsigned)W);
            abase[s] = inb[s] ? ((size_t)(sb[s] * H + ys) * W + xs) * CIN : 0;
        }

        for (int cb = 0; cb < CB; ++cb) {
            // ---- stage A: 16 ushorts per slot = two short8 (FIXED coverage)
            #pragma unroll
            for (int s = 0; s < SLOTS; ++s) {
                int idx  = tid + s * 256;
                int pl   = idx >> 1;
                int half = idx & 1;
                short8 v0 = {0, 0, 0, 0, 0, 0, 0, 0};
                short8 v1 = {0, 0, 0, 0, 0, 0, 0, 0};
                if (inb[s]) {
                    const ushort* gp = in + abase[s] + cb * 32 + half * 16;
                    v0 = *(const short8*)gp;
                    v1 = *(const short8*)(gp + 8);
                }
                *(short8*)&sA[pl * 40 + half * 16]     = v0;
                *(short8*)&sA[pl * 40 + half * 16 + 8] = v1;
            }
            // ---- stage B: same fixed coverage
            for (int idx = tid; idx < BN * 2; idx += 256) {
                int co   = idx >> 1;
                int half = idx & 1;
                size_t off = ((size_t)(t * CB + cb) * COUT + co0 + co) * 32 + half * 16;
                *(short8*)&sB[co * 40 + half * 16]     = *(const short8*)(wp + off);
                *(short8*)&sB[co * 40 + half * 16 + 8] = *(const short8*)(wp + off + 8);
            }
            __syncthreads();

            short8 af[4], bf4[4];
            #pragma unroll
            for (int i = 0; i < 4; ++i) {
                af[i]  = *(const short8*)&sA[(wm * 64 + i * 16 + col) * 40 + quad * 8];
                bf4[i] = *(const short8*)&sB[(wn * 64 + i * 16 + col) * 40 + quad * 8];
            }
            #pragma unroll
            for (int mt = 0; mt < 4; ++mt)
                #pragma unroll
                for (int nt = 0; nt < 4; ++nt)
                    acc[mt][nt] = __builtin_amdgcn_mfma_f32_16x16x32_bf16(
                        af[mt], bf4[nt], acc[mt][nt], 0, 0, 0);
            __syncthreads();
        }
    }

    if (!FINAL) {
        ushort* outp = (ushort*)outv;
        #pragma unroll
        for (int mt = 0; mt < 4; ++mt) {
            #pragma unroll
            for (int nt = 0; nt < 4; ++nt) {
                int co = co0 + wn * 64 + nt * 16 + col;
                float bv = bias[co];
                #pragma unroll
                for (int r2 = 0; r2 < 4; ++r2) {
                    int m = bm0 + wm * 64 + mt * 16 + quad * 4 + r2;
                    float vv = acc[mt][nt][r2] + bv;
                    vv = vv > 0.f ? vv : 0.f;
                    outp[(size_t)m * COUT + co] = f2b(vv);
                }
            }
        }
    } else {
        float* outp = (float*)outv;   // fp32 NCHW direct to d_out
        #pragma unroll
        for (int mt = 0; mt < 4; ++mt) {
            int p0 = bm0 + wm * 64 + mt * 16 + quad * 4;
            int bb = p0 / (H * W);
            int rp = p0 - bb * (H * W);
            #pragma unroll
            for (int nt = 0; nt < 4; ++nt) {
                int co = co0 + wn * 64 + nt * 16 + col;
                float bv = bias[co];
                f32x4 vv;
                #pragma unroll
                for (int r2 = 0; r2 < 4; ++r2) {
                    float z = acc[mt][nt][r2] + bv;
                    vv[r2] = z > 0.f ? z : 0.f;
                }
                *(f32x4*)&outp[((size_t)(bb * COUT + co)) * (H * W) + rp] = vv;
            }
        }
    }
}

// ---------------------------------------------------------------------------
extern "C" void kernel_launch(void* const* d_in, const int* in_sizes, int n_in,
                              void* d_out, int out_size, void* d_ws, size_t ws_size,
                              hipStream_t stream)
{
    const float* x    = (const float*)d_in[0];
    const int*   mask = (const int*)d_in[1];
    const float* Wt[10];
    const float* bs[10];
    for (int i = 0; i < 10; ++i) {
        Wt[i] = (const float*)d_in[2 + 2 * i];
        bs[i] = (const float*)d_in[3 + 2 * i];
    }

    // workspace: two bf16 activation buffers + repacked weights
    const size_t ACT = (size_t)4 * 384 * 384 * 64;   // ushorts (75.5 MB each)
    ushort* A  = (ushort*)d_ws;
    ushort* Bb = A + ACT;
    ushort* wpbase = Bb + ACT;

    static const int cins[10]  = {3, 64, 64, 128, 128, 256, 256, 256, 512, 512};
    static const int couts[10] = {64, 64, 128, 128, 256, 256, 256, 512, 512, 512};
    ushort* wp[10];
    size_t wo = 0;
    for (int l = 1; l < 10; ++l) {
        wp[l] = wpbase + wo;
        wo += (size_t)couts[l] * cins[l] * 9;
    }
    for (int l = 1; l < 10; ++l) {
        int n = couts[l] * cins[l] * 9;
        repack_w<<<(n + 255) / 256, 256, 0, stream>>>(Wt[l], wp[l], cins[l], couts[l]);
    }

    // L1: fp32 NCHW -> bf16 NHWC
    l1_conv<<<dim3(24 * 24, 1, 4), 256, 0, stream>>>(x, Wt[0], bs[0], A);

    // L2: 64->64 @384 (BM=256, BN=64)
    conv_mfma<256, 64, 64, 64, 384, 384, false, false>
        <<<dim3(589824 / 256, 1), 256, 0, stream>>>(A, wp[1], bs[1], Bb, nullptr);
    maxpool_nhwc<<<(4 * 192 * 192 * 8 + 255) / 256, 256, 0, stream>>>(Bb, A, 192, 192, 64);

    // L3: 64->128 @192
    conv_mfma<128, 128, 64, 128, 192, 192, false, false>
        <<<dim3(1152, 1), 256, 0, stream>>>(A, wp[2], bs[2], Bb, nullptr);
    // L4: 128->128 @192
    conv_mfma<128, 128, 128, 128, 192, 192, false, false>
        <<<dim3(1152, 1), 256, 0, stream>>>(Bb, wp[3], bs[3], A, nullptr);
    maxpool_nhwc<<<(4 * 96 * 96 * 16 + 255) / 256, 256, 0, stream>>>(A, Bb, 96, 96, 128);

    // L5: 128->256 @96
    conv_mfma<128, 128, 128, 256, 96, 96, false, false>
        <<<dim3(288, 2), 256, 0, stream>>>(Bb, wp[4], bs[4], A, nullptr);
    // L6: 256->256
    conv_mfma<128, 128, 256, 256, 96, 96, false, false>
        <<<dim3(288, 2), 256, 0, stream>>>(A, wp[5], bs[5], Bb, nullptr);
    // L7: 256->256
    conv_mfma<128, 128, 256, 256, 96, 96, false, false>
        <<<dim3(288, 2), 256, 0, stream>>>(Bb, wp[6], bs[6], A, nullptr);

    // irregular pool
    irpool_nhwc<<<(4 * 96 * 96 * 32 + 255) / 256, 256, 0, stream>>>(A, mask, Bb);

    // L8: gconv 256->512
    conv_mfma<128, 128, 256, 512, 96, 96, true, false>
        <<<dim3(288, 4), 256, 0, stream>>>(Bb, wp[7], bs[7], A, mask);
    // L9: gconv 512->512
    conv_mfma<128, 128, 512, 512, 96, 96, true, false>
        <<<dim3(288, 4), 256, 0, stream>>>(A, wp[8], bs[8], Bb, mask);
    // L10: gconv 512->512 -> fp32 NCHW d_out
    conv_mfma<128, 128, 512, 512, 96, 96, true, true>
        <<<dim3(288, 4), 256, 0, stream>>>(Bb, wp[9], bs[9], d_out, mask);

    (void)in_sizes; (void)n_in; (void)out_size; (void)ws_size;
}

// Round 5
// 1340.893 us; speedup vs baseline: 15.8555x; 1.1698x over previous
//
#include <hip/hip_runtime.h>

// ---------------------------------------------------------------------------
// Round 5: tap-reuse restructure. Block = TRx16 spatial tile; the halo'd
// input tile (32 channels) is staged into LDS ONCE per channel-block, then
// all 9 taps read A-fragments from resident LDS (per-pixel dilation = per-lane
// LDS address offset). Only the 8KB B-tile is staged per tap (reg-prefetched
// before the barrier). Cuts the im2col HBM gather 9x and its latency events.
// ---------------------------------------------------------------------------

typedef __attribute__((ext_vector_type(8))) short short8;
typedef __attribute__((ext_vector_type(4))) float f32x4;

__device__ __forceinline__ float b2f(ushort u) {
    return __uint_as_float(((unsigned)u) << 16);
}
__device__ __forceinline__ ushort f2b(float f) {   // round-to-nearest-even
    unsigned x = __float_as_uint(f);
    x += 0x7FFFu + ((x >> 16) & 1u);
    return (ushort)(x >> 16);
}
__device__ __forceinline__ ushort bmax(ushort a, ushort b) {
    return b2f(a) > b2f(b) ? a : b;
}

// ------------- repack weights [co][ci][t] f32 -> [t][cb][co][ci32] bf16 -----
__global__ __launch_bounds__(256)
void repack_w(const float* __restrict__ w, ushort* __restrict__ wp, int Cin, int Cout)
{
    int n = Cout * Cin * 9;
    int i = blockIdx.x * 256 + threadIdx.x;
    if (i >= n) return;
    int CBl = Cin / 32;
    int c   = i & 31;
    int co  = (i >> 5) % Cout;
    int cbt = i / (32 * Cout);
    int cb  = cbt % CBl;
    int t   = cbt / CBl;
    int ci  = cb * 32 + c;
    wp[i] = f2b(w[((size_t)co * Cin + ci) * 9 + t]);
}

// ------------- L1: 3->64 direct conv, fp32 NCHW in -> bf16 NHWC out ---------
__global__ __launch_bounds__(256)
void l1_conv(const float* __restrict__ in, const float* __restrict__ w,
             const float* __restrict__ bias, ushort* __restrict__ out)
{
    const int H = 384, W = 384;
    __shared__ float s[3][18][18];
    const int tid = threadIdx.x;
    const int tilesX = W / 16;
    const int x0 = (blockIdx.x % tilesX) * 16;
    const int y0 = (blockIdx.x / tilesX) * 16;
    const int b  = blockIdx.z;

    for (int i = tid; i < 3 * 18 * 18; i += 256) {
        int ci = i / (18 * 18);
        int r  = i % (18 * 18);
        int iy = r / 18, ix = r % 18;
        int gy = y0 - 1 + iy, gx = x0 - 1 + ix;
        float v = 0.f;
        if ((unsigned)gy < (unsigned)H && (unsigned)gx < (unsigned)W)
            v = in[((size_t)(b * 3 + ci) * H + gy) * W + gx];
        s[ci][iy][ix] = v;
    }
    __syncthreads();

    const int tx = tid & 15, ty = tid >> 4;
    float iv[3][3][3];
    #pragma unroll
    for (int ci = 0; ci < 3; ++ci)
        #pragma unroll
        for (int ky = 0; ky < 3; ++ky)
            #pragma unroll
            for (int kx = 0; kx < 3; ++kx)
                iv[ci][ky][kx] = s[ci][ty + ky][tx + kx];

    size_t pix = ((size_t)(b * H + y0 + ty) * W + x0 + tx);
    #pragma unroll
    for (int c4 = 0; c4 < 4; ++c4) {
        __align__(16) ushort ob[16];
        #pragma unroll
        for (int co = 0; co < 16; ++co) {
            int coG = c4 * 16 + co;
            float a = bias[coG];
            #pragma unroll
            for (int ci = 0; ci < 3; ++ci)
                #pragma unroll
                for (int ky = 0; ky < 3; ++ky)
                    #pragma unroll
                    for (int kx = 0; kx < 3; ++kx)
                        a = fmaf(w[((size_t)coG * 3 + ci) * 9 + ky * 3 + kx],
                                 iv[ci][ky][kx], a);
            a = a > 0.f ? a : 0.f;
            ob[co] = f2b(a);
        }
        *(short8*)&out[pix * 64 + c4 * 16]     = *(short8*)&ob[0];
        *(short8*)&out[pix * 64 + c4 * 16 + 8] = *(short8*)&ob[8];
    }
}

// ------------- 2x2 maxpool, bf16 NHWC ---------------------------------------
__global__ __launch_bounds__(256)
void maxpool_nhwc(const ushort* __restrict__ in, ushort* __restrict__ out,
                  int Ho, int Wo, int C)
{
    int n = 4 * Ho * Wo * (C / 8);
    int i = blockIdx.x * 256 + threadIdx.x;
    if (i >= n) return;
    int c8 = i % (C / 8);
    int pi = i / (C / 8);
    int x = pi % Wo, y = (pi / Wo) % Ho, b = pi / (Wo * Ho);
    int Hi = Ho * 2, Wi = Wo * 2;
    const ushort* p = in + ((size_t)(b * Hi + 2 * y) * Wi + 2 * x) * C + c8 * 8;
    short8 v00 = *(const short8*)p;
    short8 v01 = *(const short8*)(p + C);
    short8 v10 = *(const short8*)(p + (size_t)Wi * C);
    short8 v11 = *(const short8*)(p + (size_t)Wi * C + C);
    short8 o;
    #pragma unroll
    for (int j = 0; j < 8; ++j)
        o[j] = (short)bmax(bmax((ushort)v00[j], (ushort)v01[j]),
                           bmax((ushort)v10[j], (ushort)v11[j]));
    *(short8*)(out + (size_t)i * 8) = o;
}

// ------------- irregular pool (mask-gated 2x2 max, replicated), NHWC --------
__global__ __launch_bounds__(256)
void irpool_nhwc(const ushort* __restrict__ in, const int* __restrict__ mask,
                 ushort* __restrict__ out)
{
    const int C = 256, H = 96, Wd = 96;
    int n = 4 * H * Wd * (C / 8);
    int i = blockIdx.x * 256 + threadIdx.x;
    if (i >= n) return;
    int c8 = i % (C / 8);
    int pi = i / (C / 8);
    int x = pi % Wd, y = (pi / Wd) % H, b = pi / (Wd * H);
    int m = mask[(b * 48 + (y >> 1)) * 48 + (x >> 1)];
    short8 o;
    if (m) {
        int y0 = y & ~1, x0 = x & ~1;
        const ushort* p = in + ((size_t)(b * H + y0) * Wd + x0) * C + c8 * 8;
        short8 v00 = *(const short8*)p;
        short8 v01 = *(const short8*)(p + C);
        short8 v10 = *(const short8*)(p + (size_t)Wd * C);
        short8 v11 = *(const short8*)(p + (size_t)Wd * C + C);
        #pragma unroll
        for (int j = 0; j < 8; ++j)
            o[j] = (short)bmax(bmax((ushort)v00[j], (ushort)v01[j]),
                               bmax((ushort)v10[j], (ushort)v11[j]));
    } else {
        o = *(const short8*)(in + (size_t)pi * C + c8 * 8);
    }
    *(short8*)(out + (size_t)pi * C + c8 * 8) = o;
}

// ------------- implicit-GEMM conv3x3, tap-reuse LDS tile, bf16 MFMA ---------
// Block = TRx16 output pixels (one batch image), 256 threads = 4 waves.
// Per 32-channel block: stage (TR+2*HA)x(16+2*HA) halo tile once; 9 taps read
// A-fragments from resident LDS (per-lane chunk offset d*(ky*CW+kx)).
// B (8KB) staged per tap, reg-prefetched before the barrier.
// All LDS rows stride 40 ushorts (80B) -> max 2-way bank alias (free).
template<int TR, int BN, int CIN, int COUT, int H, int W, bool GCONV, bool FINAL>
__global__ __launch_bounds__(256)
void conv_mfma(const ushort* __restrict__ in, const ushort* __restrict__ wp,
               const float* __restrict__ bias, void* __restrict__ outv,
               const int* __restrict__ mask)
{
    constexpr int BM  = TR * 16;
    constexpr int CB  = CIN / 32;
    constexpr int HA  = GCONV ? 2 : 1;
    constexpr int CW  = 16 + 2 * HA;     // halo cols
    constexpr int CR  = TR + 2 * HA;     // halo rows
    constexpr int NCH = CR * CW;         // pixel chunks in tile
    constexpr int WM  = BM / 64;         // waves along M (2 or 4)

    __shared__ __align__(16) ushort sA[NCH * 40];
    __shared__ __align__(16) ushort sB[BN * 40];

    const int tid  = threadIdx.x;
    const int lane = tid & 63;
    const int wv   = tid >> 6;
    const int wm   = wv % WM;
    const int wn   = wv / WM;
    const int col  = lane & 15;
    const int quad = lane >> 4;

    const int tiles_x = W / 16, tiles_y = H / TR;
    int sp = blockIdx.x;
    const int b  = sp / (tiles_x * tiles_y);
    int rr = sp - b * tiles_x * tiles_y;
    const int ty = rr / tiles_x;
    const int tx = rr - ty * tiles_x;
    const int y0 = ty * TR, x0 = tx * 16;
    const int co0 = blockIdx.y * BN;

    // per-lane dilation + base chunk for A-operand pixels (row wm*4+mt, x col)
    int dA[4], aoff[4];
    #pragma unroll
    for (int mt = 0; mt < 4; ++mt) {
        dA[mt] = 1;
        if (GCONV) {
            int y = y0 + wm * 4 + mt, x = x0 + col;
            dA[mt] = mask[(b * (H / 2) + (y >> 1)) * (W / 2) + (x >> 1)] ? 2 : 1;
        }
        aoff[mt] = (HA + wm * 4 + mt) * CW + HA + col;
    }

    f32x4 acc[4][4];
    #pragma unroll
    for (int i = 0; i < 4; ++i)
        #pragma unroll
        for (int j = 0; j < 4; ++j)
            acc[i][j] = (f32x4){0.f, 0.f, 0.f, 0.f};

    for (int cb = 0; cb < CB; ++cb) {
        __syncthreads();   // prior cb's A-readers done before overwrite
        // ---- stage A: halo tile, 32 channels, once per cb ----
        for (int i = tid; i < NCH * 4; i += 256) {
            int chunk = i >> 2, part = i & 3;
            int yy = chunk / CW, xx = chunk - yy * CW;
            int gy = y0 - HA + yy, gx = x0 - HA + xx;
            short8 v = {0, 0, 0, 0, 0, 0, 0, 0};
            if ((unsigned)gy < (unsigned)H && (unsigned)gx < (unsigned)W)
                v = *(const short8*)(in + ((size_t)(b * H + gy) * W + gx) * CIN
                                     + cb * 32 + part * 8);
            *(short8*)&sA[chunk * 40 + part * 8] = v;
        }

        #pragma unroll
        for (int t = 0; t < 9; ++t) {
            const int ky = t / 3 - 1, kx = t % 3 - 1;
            // B prefetch to regs (issued before the barrier)
            short8 b0 = {0,0,0,0,0,0,0,0}, b1 = {0,0,0,0,0,0,0,0};
            int co = tid >> 1, half = tid & 1;
            if (BN * 2 == 256 || tid < BN * 2) {
                const ushort* gp = wp + ((size_t)(t * CB + cb) * COUT + co0 + co) * 32
                                   + half * 16;
                b0 = *(const short8*)gp;
                b1 = *(const short8*)(gp + 8);
            }
            __syncthreads();   // prior tap's sB readers done (t=0: nothing)
            if (BN * 2 == 256 || tid < BN * 2) {
                *(short8*)&sB[co * 40 + half * 16]     = b0;
                *(short8*)&sB[co * 40 + half * 16 + 8] = b1;
            }
            __syncthreads();   // sB (and at t=0, sA) visible

            short8 af[4], bf4[4];
            #pragma unroll
            for (int i = 0; i < 4; ++i) {
                int chunk = aoff[i] + dA[i] * (ky * CW + kx);
                af[i]  = *(const short8*)&sA[chunk * 40 + quad * 8];
                bf4[i] = *(const short8*)&sB[(wn * 64 + i * 16 + col) * 40 + quad * 8];
            }
            #pragma unroll
            for (int mt = 0; mt < 4; ++mt)
                #pragma unroll
                for (int nt = 0; nt < 4; ++nt)
                    acc[mt][nt] = __builtin_amdgcn_mfma_f32_16x16x32_bf16(
                        af[mt], bf4[nt], acc[mt][nt], 0, 0, 0);
        }
    }

    // ---- epilogue: pixel (b, y0 + wm*4 + mt, x0 + quad*4 + r2) ----
    if (!FINAL) {
        ushort* outp = (ushort*)outv;
        #pragma unroll
        for (int mt = 0; mt < 4; ++mt) {
            int y = y0 + wm * 4 + mt;
            #pragma unroll
            for (int nt = 0; nt < 4; ++nt) {
                int co = co0 + wn * 64 + nt * 16 + col;
                float bv = bias[co];
                #pragma unroll
                for (int r2 = 0; r2 < 4; ++r2) {
                    int x = x0 + quad * 4 + r2;
                    float vv = acc[mt][nt][r2] + bv;
                    vv = vv > 0.f ? vv : 0.f;
                    outp[((size_t)(b * H + y) * W + x) * COUT + co] = f2b(vv);
                }
            }
        }
    } else {
        float* outp = (float*)outv;   // fp32 NCHW direct to d_out
        #pragma unroll
        for (int mt = 0; mt < 4; ++mt) {
            int y = y0 + wm * 4 + mt;
            #pragma unroll
            for (int nt = 0; nt < 4; ++nt) {
                int co = co0 + wn * 64 + nt * 16 + col;
                float bv = bias[co];
                f32x4 vv;
                #pragma unroll
                for (int r2 = 0; r2 < 4; ++r2) {
                    float z = acc[mt][nt][r2] + bv;
                    vv[r2] = z > 0.f ? z : 0.f;
                }
                *(f32x4*)&outp[((size_t)(b * COUT + co) * H + y) * W + x0 + quad * 4] = vv;
            }
        }
    }
}

// ---------------------------------------------------------------------------
extern "C" void kernel_launch(void* const* d_in, const int* in_sizes, int n_in,
                              void* d_out, int out_size, void* d_ws, size_t ws_size,
                              hipStream_t stream)
{
    const float* x    = (const float*)d_in[0];
    const int*   mask = (const int*)d_in[1];
    const float* Wt[10];
    const float* bs[10];
    for (int i = 0; i < 10; ++i) {
        Wt[i] = (const float*)d_in[2 + 2 * i];
        bs[i] = (const float*)d_in[3 + 2 * i];
    }

    // workspace: two bf16 activation buffers + repacked weights
    const size_t ACT = (size_t)4 * 384 * 384 * 64;   // ushorts
    ushort* A  = (ushort*)d_ws;
    ushort* Bb = A + ACT;
    ushort* wpbase = Bb + ACT;

    static const int cins[10]  = {3, 64, 64, 128, 128, 256, 256, 256, 512, 512};
    static const int couts[10] = {64, 64, 128, 128, 256, 256, 256, 512, 512, 512};
    ushort* wp[10];
    size_t wo = 0;
    for (int l = 1; l < 10; ++l) {
        wp[l] = wpbase + wo;
        wo += (size_t)couts[l] * cins[l] * 9;
    }
    for (int l = 1; l < 10; ++l) {
        int n = couts[l] * cins[l] * 9;
        repack_w<<<(n + 255) / 256, 256, 0, stream>>>(Wt[l], wp[l], cins[l], couts[l]);
    }

    // L1: fp32 NCHW -> bf16 NHWC
    l1_conv<<<dim3(24 * 24, 1, 4), 256, 0, stream>>>(x, Wt[0], bs[0], A);

    // L2: 64->64 @384 (tile 16x16, BN=64)
    conv_mfma<16, 64, 64, 64, 384, 384, false, false>
        <<<dim3(4 * 24 * 24, 1), 256, 0, stream>>>(A, wp[1], bs[1], Bb, nullptr);
    maxpool_nhwc<<<(4 * 192 * 192 * 8 + 255) / 256, 256, 0, stream>>>(Bb, A, 192, 192, 64);

    // L3: 64->128 @192 (tile 8x16, BN=128)
    conv_mfma<8, 128, 64, 128, 192, 192, false, false>
        <<<dim3(4 * 24 * 12, 1), 256, 0, stream>>>(A, wp[2], bs[2], Bb, nullptr);
    // L4: 128->128 @192
    conv_mfma<8, 128, 128, 128, 192, 192, false, false>
        <<<dim3(4 * 24 * 12, 1), 256, 0, stream>>>(Bb, wp[3], bs[3], A, nullptr);
    maxpool_nhwc<<<(4 * 96 * 96 * 16 + 255) / 256, 256, 0, stream>>>(A, Bb, 96, 96, 128);

    // L5: 128->256 @96
    conv_mfma<8, 128, 128, 256, 96, 96, false, false>
        <<<dim3(4 * 12 * 6, 2), 256, 0, stream>>>(Bb, wp[4], bs[4], A, nullptr);
    // L6: 256->256
    conv_mfma<8, 128, 256, 256, 96, 96, false, false>
        <<<dim3(4 * 12 * 6, 2), 256, 0, stream>>>(A, wp[5], bs[5], Bb, nullptr);
    // L7: 256->256
    conv_mfma<8, 128, 256, 256, 96, 96, false, false>
        <<<dim3(4 * 12 * 6, 2), 256, 0, stream>>>(Bb, wp[6], bs[6], A, nullptr);

    // irregular pool
    irpool_nhwc<<<(4 * 96 * 96 * 32 + 255) / 256, 256, 0, stream>>>(A, mask, Bb);

    // L8: gconv 256->512
    conv_mfma<8, 128, 256, 512, 96, 96, true, false>
        <<<dim3(4 * 12 * 6, 4), 256, 0, stream>>>(Bb, wp[7], bs[7], A, mask);
    // L9: gconv 512->512
    conv_mfma<8, 128, 512, 512, 96, 96, true, false>
        <<<dim3(4 * 12 * 6, 4), 256, 0, stream>>>(A, wp[8], bs[8], Bb, mask);
    // L10: gconv 512->512 -> fp32 NCHW d_out
    conv_mfma<8, 128, 512, 512, 96, 96, true, true>
        <<<dim3(4 * 12 * 6, 4), 256, 0, stream>>>(Bb, wp[9], bs[9], d_out, mask);

    (void)in_sizes; (void)n_in; (void)out_size; (void)ws_size;
}

// Round 6
// 959.273 us; speedup vs baseline: 22.1631x; 1.3978x over previous
//
#include <hip/hip_runtime.h>

// ---------------------------------------------------------------------------
// Round 6: barrier-cut K-loop. Per channel-block, B is staged per TAP-ROW
// (3 taps at once, single LDS buffer) with register prefetch of the next
// row's B (and the next cb's A halo) issued before the MFMA section.
// Barriers per cb: 19 -> 6, with 48 MFMAs/wave between barriers.
// LDS ~50KB -> 3 blocks/CU so residual stalls overlap across blocks.
// ---------------------------------------------------------------------------

typedef __attribute__((ext_vector_type(8))) short short8;
typedef __attribute__((ext_vector_type(4))) float f32x4;

__device__ __forceinline__ float b2f(ushort u) {
    return __uint_as_float(((unsigned)u) << 16);
}
__device__ __forceinline__ ushort f2b(float f) {   // round-to-nearest-even
    unsigned x = __float_as_uint(f);
    x += 0x7FFFu + ((x >> 16) & 1u);
    return (ushort)(x >> 16);
}
__device__ __forceinline__ ushort bmax(ushort a, ushort b) {
    return b2f(a) > b2f(b) ? a : b;
}

// ------------- repack weights [co][ci][t] f32 -> [t][cb][co][ci32] bf16 -----
__global__ __launch_bounds__(256)
void repack_w(const float* __restrict__ w, ushort* __restrict__ wp, int Cin, int Cout)
{
    int n = Cout * Cin * 9;
    int i = blockIdx.x * 256 + threadIdx.x;
    if (i >= n) return;
    int CBl = Cin / 32;
    int c   = i & 31;
    int co  = (i >> 5) % Cout;
    int cbt = i / (32 * Cout);
    int cb  = cbt % CBl;
    int t   = cbt / CBl;
    int ci  = cb * 32 + c;
    wp[i] = f2b(w[((size_t)co * Cin + ci) * 9 + t]);
}

// ------------- L1: 3->64 direct conv, fp32 NCHW in -> bf16 NHWC out ---------
__global__ __launch_bounds__(256)
void l1_conv(const float* __restrict__ in, const float* __restrict__ w,
             const float* __restrict__ bias, ushort* __restrict__ out)
{
    const int H = 384, W = 384;
    __shared__ float s[3][18][18];
    const int tid = threadIdx.x;
    const int tilesX = W / 16;
    const int x0 = (blockIdx.x % tilesX) * 16;
    const int y0 = (blockIdx.x / tilesX) * 16;
    const int b  = blockIdx.z;

    for (int i = tid; i < 3 * 18 * 18; i += 256) {
        int ci = i / (18 * 18);
        int r  = i % (18 * 18);
        int iy = r / 18, ix = r % 18;
        int gy = y0 - 1 + iy, gx = x0 - 1 + ix;
        float v = 0.f;
        if ((unsigned)gy < (unsigned)H && (unsigned)gx < (unsigned)W)
            v = in[((size_t)(b * 3 + ci) * H + gy) * W + gx];
        s[ci][iy][ix] = v;
    }
    __syncthreads();

    const int tx = tid & 15, ty = tid >> 4;
    float iv[3][3][3];
    #pragma unroll
    for (int ci = 0; ci < 3; ++ci)
        #pragma unroll
        for (int ky = 0; ky < 3; ++ky)
            #pragma unroll
            for (int kx = 0; kx < 3; ++kx)
                iv[ci][ky][kx] = s[ci][ty + ky][tx + kx];

    size_t pix = ((size_t)(b * H + y0 + ty) * W + x0 + tx);
    #pragma unroll
    for (int c4 = 0; c4 < 4; ++c4) {
        __align__(16) ushort ob[16];
        #pragma unroll
        for (int co = 0; co < 16; ++co) {
            int coG = c4 * 16 + co;
            float a = bias[coG];
            #pragma unroll
            for (int ci = 0; ci < 3; ++ci)
                #pragma unroll
                for (int ky = 0; ky < 3; ++ky)
                    #pragma unroll
                    for (int kx = 0; kx < 3; ++kx)
                        a = fmaf(w[((size_t)coG * 3 + ci) * 9 + ky * 3 + kx],
                                 iv[ci][ky][kx], a);
            a = a > 0.f ? a : 0.f;
            ob[co] = f2b(a);
        }
        *(short8*)&out[pix * 64 + c4 * 16]     = *(short8*)&ob[0];
        *(short8*)&out[pix * 64 + c4 * 16 + 8] = *(short8*)&ob[8];
    }
}

// ------------- 2x2 maxpool, bf16 NHWC ---------------------------------------
__global__ __launch_bounds__(256)
void maxpool_nhwc(const ushort* __restrict__ in, ushort* __restrict__ out,
                  int Ho, int Wo, int C)
{
    int n = 4 * Ho * Wo * (C / 8);
    int i = blockIdx.x * 256 + threadIdx.x;
    if (i >= n) return;
    int c8 = i % (C / 8);
    int pi = i / (C / 8);
    int x = pi % Wo, y = (pi / Wo) % Ho, b = pi / (Wo * Ho);
    int Hi = Ho * 2, Wi = Wo * 2;
    const ushort* p = in + ((size_t)(b * Hi + 2 * y) * Wi + 2 * x) * C + c8 * 8;
    short8 v00 = *(const short8*)p;
    short8 v01 = *(const short8*)(p + C);
    short8 v10 = *(const short8*)(p + (size_t)Wi * C);
    short8 v11 = *(const short8*)(p + (size_t)Wi * C + C);
    short8 o;
    #pragma unroll
    for (int j = 0; j < 8; ++j)
        o[j] = (short)bmax(bmax((ushort)v00[j], (ushort)v01[j]),
                           bmax((ushort)v10[j], (ushort)v11[j]));
    *(short8*)(out + (size_t)i * 8) = o;
}

// ------------- irregular pool (mask-gated 2x2 max, replicated), NHWC --------
__global__ __launch_bounds__(256)
void irpool_nhwc(const ushort* __restrict__ in, const int* __restrict__ mask,
                 ushort* __restrict__ out)
{
    const int C = 256, H = 96, Wd = 96;
    int n = 4 * H * Wd * (C / 8);
    int i = blockIdx.x * 256 + threadIdx.x;
    if (i >= n) return;
    int c8 = i % (C / 8);
    int pi = i / (C / 8);
    int x = pi % Wd, y = (pi / Wd) % H, b = pi / (Wd * H);
    int m = mask[(b * 48 + (y >> 1)) * 48 + (x >> 1)];
    short8 o;
    if (m) {
        int y0 = y & ~1, x0 = x & ~1;
        const ushort* p = in + ((size_t)(b * H + y0) * Wd + x0) * C + c8 * 8;
        short8 v00 = *(const short8*)p;
        short8 v01 = *(const short8*)(p + C);
        short8 v10 = *(const short8*)(p + (size_t)Wd * C);
        short8 v11 = *(const short8*)(p + (size_t)Wd * C + C);
        #pragma unroll
        for (int j = 0; j < 8; ++j)
            o[j] = (short)bmax(bmax((ushort)v00[j], (ushort)v01[j]),
                               bmax((ushort)v10[j], (ushort)v11[j]));
    } else {
        o = *(const short8*)(in + (size_t)pi * C + c8 * 8);
    }
    *(short8*)(out + (size_t)pi * C + c8 * 8) = o;
}

// ------------- implicit-GEMM conv3x3, tap-row staged, bf16 MFMA -------------
// Block = TRx16 output pixels, 256 threads = 4 waves, wave tile 64x64.
// Per cb: A halo staged once; B staged per tap-ROW (3 taps, single buffer)
// with register prefetch of next row's B / next cb's A before the MFMA
// section. 6 barriers per cb, 48 MFMA per wave between barriers.
template<int TR, int BN, int CIN, int COUT, int H, int W, bool GCONV, bool FINAL>
__global__ __launch_bounds__(256)
void conv_mfma(const ushort* __restrict__ in, const ushort* __restrict__ wp,
               const float* __restrict__ bias, void* __restrict__ outv,
               const int* __restrict__ mask)
{
    constexpr int BM  = TR * 16;
    constexpr int CB  = CIN / 32;
    constexpr int HA  = GCONV ? 2 : 1;
    constexpr int CW  = 16 + 2 * HA;
    constexpr int CR  = TR + 2 * HA;
    constexpr int NCH = CR * CW;
    constexpr int WM  = BM / 64;
    constexpr int NSA = NCH * 4;              // short8 chunks in sA
    constexpr int NSLA = (NSA + 255) / 256;
    constexpr int NSB = 3 * BN * 2;           // 16-ushort half-slots per row
    constexpr int NSLB = (NSB + 255) / 256;

    __shared__ __align__(16) ushort sA[NCH * 40];
    __shared__ __align__(16) ushort sB[3 * BN * 40];

    const int tid  = threadIdx.x;
    const int lane = tid & 63;
    const int wv   = tid >> 6;
    const int wm   = wv % WM;
    const int wn   = wv / WM;
    const int col  = lane & 15;
    const int quad = lane >> 4;

    const int tiles_x = W / 16, tiles_y = H / TR;
    int sp = blockIdx.x;
    const int b  = sp / (tiles_x * tiles_y);
    int rr = sp - b * tiles_x * tiles_y;
    const int ty = rr / tiles_x;
    const int tx = rr - ty * tiles_x;
    const int y0 = ty * TR, x0 = tx * 16;
    const int co0 = blockIdx.y * BN;

    int dA[4], aoff[4];
    #pragma unroll
    for (int mt = 0; mt < 4; ++mt) {
        dA[mt] = 1;
        if (GCONV) {
            int y = y0 + wm * 4 + mt, x = x0 + col;
            dA[mt] = mask[(b * (H / 2) + (y >> 1)) * (W / 2) + (x >> 1)] ? 2 : 1;
        }
        aoff[mt] = (HA + wm * 4 + mt) * CW + HA + col;
    }

    short8 pA[NSLA];
    short8 pB[NSLB][2];

    auto loadA = [&](int cb) {
        #pragma unroll
        for (int k = 0; k < NSLA; ++k) {
            int i = tid + k * 256;
            short8 v = {0, 0, 0, 0, 0, 0, 0, 0};
            if (NSA == NSLA * 256 || i < NSA) {
                int chunk = i >> 2, part = i & 3;
                int yy = chunk / CW, xx = chunk - yy * CW;
                int gy = y0 - HA + yy, gx = x0 - HA + xx;
                if ((unsigned)gy < (unsigned)H && (unsigned)gx < (unsigned)W)
                    v = *(const short8*)(in + ((size_t)(b * H + gy) * W + gx) * CIN
                                         + cb * 32 + part * 8);
            }
            pA[k] = v;
        }
    };
    auto storeA = [&]() {
        #pragma unroll
        for (int k = 0; k < NSLA; ++k) {
            int i = tid + k * 256;
            if (NSA == NSLA * 256 || i < NSA) {
                int chunk = i >> 2, part = i & 3;
                *(short8*)&sA[chunk * 40 + part * 8] = pA[k];
            }
        }
    };
    auto loadB = [&](int s) {
        int cb = s / 3, row = s % 3;
        #pragma unroll
        for (int k = 0; k < NSLB; ++k) {
            int i = tid + k * 256;
            if (NSB == NSLB * 256 || i < NSB) {
                int tl = i / (BN * 2);
                int r  = i % (BN * 2);
                int co = r >> 1, half = r & 1;
                const ushort* gp = wp
                    + ((size_t)((row * 3 + tl) * CB + cb) * COUT + co0 + co) * 32
                    + half * 16;
                pB[k][0] = *(const short8*)gp;
                pB[k][1] = *(const short8*)(gp + 8);
            }
        }
    };
    auto storeB = [&]() {
        #pragma unroll
        for (int k = 0; k < NSLB; ++k) {
            int i = tid + k * 256;
            if (NSB == NSLB * 256 || i < NSB) {
                int tl = i / (BN * 2);
                int r  = i % (BN * 2);
                int co = r >> 1, half = r & 1;
                *(short8*)&sB[(tl * BN + co) * 40 + half * 16]     = pB[k][0];
                *(short8*)&sB[(tl * BN + co) * 40 + half * 16 + 8] = pB[k][1];
            }
        }
    };

    f32x4 acc[4][4];
    #pragma unroll
    for (int i = 0; i < 4; ++i)
        #pragma unroll
        for (int j = 0; j < 4; ++j)
            acc[i][j] = (f32x4){0.f, 0.f, 0.f, 0.f};

    // prologue
    loadA(0);
    loadB(0);
    storeA();
    storeB();
    __syncthreads();

    for (int s = 0; s < 3 * CB; ++s) {
        const int row  = s % 3;
        const bool last = (s == 3 * CB - 1);
        if (!last) {
            loadB(s + 1);                 // global prefetch, lands at storeB
            if (row == 2) loadA(s / 3 + 1);
        }
        const int ky = row - 1;
        #pragma unroll
        for (int j = 0; j < 3; ++j) {
            const int kx = j - 1;
            short8 af[4], bf4[4];
            #pragma unroll
            for (int i = 0; i < 4; ++i) {
                int chunk = aoff[i] + dA[i] * (ky * CW + kx);
                af[i]  = *(const short8*)&sA[chunk * 40 + quad * 8];
                bf4[i] = *(const short8*)&sB[(j * BN + wn * 64 + i * 16 + col) * 40
                                             + quad * 8];
            }
            #pragma unroll
            for (int mt = 0; mt < 4; ++mt)
                #pragma unroll
                for (int nt = 0; nt < 4; ++nt)
                    acc[mt][nt] = __builtin_amdgcn_mfma_f32_16x16x32_bf16(
                        af[mt], bf4[nt], acc[mt][nt], 0, 0, 0);
        }
        if (!last) {
            __syncthreads();              // all reads of sA/sB done
            storeB();
            if (row == 2) storeA();
            __syncthreads();              // writes visible
        }
    }

    // ---- epilogue ----
    if (!FINAL) {
        ushort* outp = (ushort*)outv;
        #pragma unroll
        for (int mt = 0; mt < 4; ++mt) {
            int y = y0 + wm * 4 + mt;
            #pragma unroll
            for (int nt = 0; nt < 4; ++nt) {
                int co = co0 + wn * 64 + nt * 16 + col;
                float bv = bias[co];
                #pragma unroll
                for (int r2 = 0; r2 < 4; ++r2) {
                    int x = x0 + quad * 4 + r2;
                    float vv = acc[mt][nt][r2] + bv;
                    vv = vv > 0.f ? vv : 0.f;
                    outp[((size_t)(b * H + y) * W + x) * COUT + co] = f2b(vv);
                }
            }
        }
    } else {
        float* outp = (float*)outv;   // fp32 NCHW direct to d_out
        #pragma unroll
        for (int mt = 0; mt < 4; ++mt) {
            int y = y0 + wm * 4 + mt;
            #pragma unroll
            for (int nt = 0; nt < 4; ++nt) {
                int co = co0 + wn * 64 + nt * 16 + col;
                float bv = bias[co];
                f32x4 vv;
                #pragma unroll
                for (int r2 = 0; r2 < 4; ++r2) {
                    float z = acc[mt][nt][r2] + bv;
                    vv[r2] = z > 0.f ? z : 0.f;
                }
                *(f32x4*)&outp[((size_t)(b * COUT + co) * H + y) * W + x0 + quad * 4] = vv;
            }
        }
    }
}

// ---------------------------------------------------------------------------
extern "C" void kernel_launch(void* const* d_in, const int* in_sizes, int n_in,
                              void* d_out, int out_size, void* d_ws, size_t ws_size,
                              hipStream_t stream)
{
    const float* x    = (const float*)d_in[0];
    const int*   mask = (const int*)d_in[1];
    const float* Wt[10];
    const float* bs[10];
    for (int i = 0; i < 10; ++i) {
        Wt[i] = (const float*)d_in[2 + 2 * i];
        bs[i] = (const float*)d_in[3 + 2 * i];
    }

    const size_t ACT = (size_t)4 * 384 * 384 * 64;   // ushorts
    ushort* A  = (ushort*)d_ws;
    ushort* Bb = A + ACT;
    ushort* wpbase = Bb + ACT;

    static const int cins[10]  = {3, 64, 64, 128, 128, 256, 256, 256, 512, 512};
    static const int couts[10] = {64, 64, 128, 128, 256, 256, 256, 512, 512, 512};
    ushort* wp[10];
    size_t wo = 0;
    for (int l = 1; l < 10; ++l) {
        wp[l] = wpbase + wo;
        wo += (size_t)couts[l] * cins[l] * 9;
    }
    for (int l = 1; l < 10; ++l) {
        int n = couts[l] * cins[l] * 9;
        repack_w<<<(n + 255) / 256, 256, 0, stream>>>(Wt[l], wp[l], cins[l], couts[l]);
    }

    // L1: fp32 NCHW -> bf16 NHWC
    l1_conv<<<dim3(24 * 24, 1, 4), 256, 0, stream>>>(x, Wt[0], bs[0], A);

    // L2: 64->64 @384 (tile 16x16, BN=64)
    conv_mfma<16, 64, 64, 64, 384, 384, false, false>
        <<<dim3(4 * 24 * 24, 1), 256, 0, stream>>>(A, wp[1], bs[1], Bb, nullptr);
    maxpool_nhwc<<<(4 * 192 * 192 * 8 + 255) / 256, 256, 0, stream>>>(Bb, A, 192, 192, 64);

    // L3: 64->128 @192 (tile 8x16, BN=128)
    conv_mfma<8, 128, 64, 128, 192, 192, false, false>
        <<<dim3(4 * 24 * 12, 1), 256, 0, stream>>>(A, wp[2], bs[2], Bb, nullptr);
    // L4: 128->128 @192
    conv_mfma<8, 128, 128, 128, 192, 192, false, false>
        <<<dim3(4 * 24 * 12, 1), 256, 0, stream>>>(Bb, wp[3], bs[3], A, nullptr);
    maxpool_nhwc<<<(4 * 96 * 96 * 16 + 255) / 256, 256, 0, stream>>>(A, Bb, 96, 96, 128);

    // L5: 128->256 @96
    conv_mfma<8, 128, 128, 256, 96, 96, false, false>
        <<<dim3(4 * 12 * 6, 2), 256, 0, stream>>>(Bb, wp[4], bs[4], A, nullptr);
    // L6: 256->256
    conv_mfma<8, 128, 256, 256, 96, 96, false, false>
        <<<dim3(4 * 12 * 6, 2), 256, 0, stream>>>(A, wp[5], bs[5], Bb, nullptr);
    // L7: 256->256
    conv_mfma<8, 128, 256, 256, 96, 96, false, false>
        <<<dim3(4 * 12 * 6, 2), 256, 0, stream>>>(Bb, wp[6], bs[6], A, nullptr);

    // irregular pool
    irpool_nhwc<<<(4 * 96 * 96 * 32 + 255) / 256, 256, 0, stream>>>(A, mask, Bb);

    // L8: gconv 256->512
    conv_mfma<8, 128, 256, 512, 96, 96, true, false>
        <<<dim3(4 * 12 * 6, 4), 256, 0, stream>>>(Bb, wp[7], bs[7], A, mask);
    // L9: gconv 512->512
    conv_mfma<8, 128, 512, 512, 96, 96, true, false>
        <<<dim3(4 * 12 * 6, 4), 256, 0, stream>>>(A, wp[8], bs[8], Bb, mask);
    // L10: gconv 512->512 -> fp32 NCHW d_out
    conv_mfma<8, 128, 512, 512, 96, 96, true, true>
        <<<dim3(4 * 12 * 6, 4), 256, 0, stream>>>(Bb, wp[9], bs[9], d_out, mask);

    (void)in_sizes; (void)n_in; (void)out_size; (void)ws_size;
}